// Round 1
// baseline (1767.383 us; speedup 1.0000x reference)
//
#include <hip/hip_runtime.h>

#define NN 100000
#define NE 1600000
#define DD 128
#define HH 16
#define CC 40
#define LL 3

__global__ void build_rowptr(const int* __restrict__ row, int* __restrict__ rp) {
    int i = blockIdx.x * blockDim.x + threadIdx.x;
    if (i > NN) return;
    int lo = 0, hi = NE;
    while (lo < hi) { int m = (lo + hi) >> 1; if (row[m] < i) lo = m + 1; else hi = m; }
    rp[i] = lo;
}

// out[n][h] = sum_k X[n][k] * W[k][h]   (N x 128) @ (128 x 16)
__launch_bounds__(256)
__global__ void gemm_dh(const float* __restrict__ X, const float* __restrict__ W,
                        float* __restrict__ out) {
    __shared__ float Ws[DD * HH];        // 8 KB
    __shared__ float Xs[16][DD + 1];     // padded: kills 4-way bank conflict on Xs[r][k]
    int t = threadIdx.x;
    for (int i = t; i < DD * HH; i += 256) Ws[i] = W[i];
    int base = blockIdx.x * 16;
    for (int i = t; i < 16 * DD; i += 256) {
        int r = i >> 7, c = i & 127;
        int g = base + r;
        Xs[r][c] = (g < NN) ? X[g * DD + c] : 0.f;
    }
    __syncthreads();
    int r = t >> 4, h = t & 15;
    float acc = 0.f;
    #pragma unroll
    for (int k = 0; k < DD; k++) acc += Xs[r][k] * Ws[k * HH + h];
    int g = base + r;
    if (g < NN) out[g * HH + h] = acc;
}

// out[n][d] = sum_k T[n][k] * W[k][d]   (N x 16) @ (16 x 128), grid-stride
__launch_bounds__(256)
__global__ void gemm_hd(const float* __restrict__ T, const float* __restrict__ W,
                        float* __restrict__ out) {
    __shared__ float Ws[HH * DD];        // 8 KB
    for (int i = threadIdx.x; i < HH * DD; i += 256) Ws[i] = W[i];
    __syncthreads();
    const int total = NN * DD;
    for (int id = blockIdx.x * 256 + threadIdx.x; id < total; id += gridDim.x * 256) {
        int n = id >> 7, d = id & 127;
        const float* tr = T + n * HH;
        float acc = 0.f;
        #pragma unroll
        for (int k = 0; k < HH; k++) acc += tr[k] * Ws[k * DD + d];
        out[id] = acc;
    }
}

// out[n][c] = sum_k T[n][k] * W[k][c]   (N x 16) @ (16 x 40), grid-stride
__launch_bounds__(256)
__global__ void gemm_hc(const float* __restrict__ T, const float* __restrict__ W,
                        float* __restrict__ out) {
    __shared__ float Ws[HH * CC];
    for (int i = threadIdx.x; i < HH * CC; i += 256) Ws[i] = W[i];
    __syncthreads();
    const int total = NN * CC;
    for (int id = blockIdx.x * 256 + threadIdx.x; id < total; id += gridDim.x * 256) {
        int n = id / CC, c = id - n * CC;
        const float* tr = T + n * HH;
        float acc = 0.f;
        #pragma unroll
        for (int k = 0; k < HH; k++) acc += tr[k] * Ws[k * CC + c];
        out[id] = acc;
    }
}

// out[i][f] = bias[f] + sum_{e in [rp[i],rp[i+1])} vals[e] * hin[col[e]][f]
// TPN lanes per node, lane = feature  (coalesced gather of hin rows)
template <int F, int TPN, bool RELU>
__launch_bounds__(256)
__global__ void spmm(const int* __restrict__ rp, const int* __restrict__ col,
                     const float* __restrict__ vals, const float* __restrict__ hin,
                     const float* __restrict__ bias, float* __restrict__ out) {
    int node = blockIdx.x * (256 / TPN) + threadIdx.x / TPN;
    int f = threadIdx.x % TPN;
    if (node >= NN) return;
    int s = rp[node], e = rp[node + 1];
    if (f < F) {
        float acc = 0.f;
        for (int j = s; j < e; j++) {
            acc += vals[j] * hin[col[j] * F + f];
        }
        acc += bias[f];
        if (RELU) acc = fmaxf(acc, 0.f);
        out[node * F + f] = acc;
    }
}

__global__ void zero_sums(float* s) { s[threadIdx.x] = 0.f; }  // <<<1,256>>>

// sums[0..127] = sum_n h[n][d] ; sums[128..255] = sum_n h[n][d]^2
__launch_bounds__(256)
__global__ void bn_reduce(const float* __restrict__ h, float* __restrict__ sums) {
    __shared__ float s1[256], s2[256];
    int d = threadIdx.x & 127;
    int half = threadIdx.x >> 7;
    int rows = (NN + gridDim.x - 1) / gridDim.x;
    int r0 = blockIdx.x * rows;
    int r1 = min(r0 + rows, NN);
    float s = 0.f, q = 0.f;
    for (int r = r0 + half; r < r1; r += 2) {
        float v = h[r * DD + d];
        s += v; q += v * v;
    }
    s1[threadIdx.x] = s; s2[threadIdx.x] = q;
    __syncthreads();
    if (threadIdx.x < 128) {
        float ss = s1[threadIdx.x] + s1[threadIdx.x + 128];
        float qq = s2[threadIdx.x] + s2[threadIdx.x + 128];
        atomicAdd(&sums[d], ss);
        atomicAdd(&sums[128 + d], qq);
    }
}

// out = relu((h - mean) * rsqrt(var+eps) * gamma + beta)
__launch_bounds__(256)
__global__ void bn_apply(const float* __restrict__ h, const float* __restrict__ sums,
                         const float* __restrict__ gamma, const float* __restrict__ beta,
                         float* __restrict__ out) {
    __shared__ float sc[DD], sh[DD];
    if (threadIdx.x < DD) {
        int d = threadIdx.x;
        float mean = sums[d] * (1.f / NN);
        float var  = sums[128 + d] * (1.f / NN) - mean * mean;
        float inv = rsqrtf(var + 1e-5f);
        float g = gamma[d] * inv;
        sc[d] = g;
        sh[d] = beta[d] - mean * g;
    }
    __syncthreads();
    const int total = NN * DD;
    for (int id = blockIdx.x * 256 + threadIdx.x; id < total; id += gridDim.x * 256) {
        int d = id & 127;
        float v = h[id] * sc[d] + sh[d];
        out[id] = fmaxf(v, 0.f);
    }
}

extern "C" void kernel_launch(void* const* d_in, const int* in_sizes, int n_in,
                              void* d_out, int out_size, void* d_ws, size_t ws_size,
                              hipStream_t stream) {
    const float* x     = (const float*)d_in[0];
    const float* vals  = (const float*)d_in[1];
    const float* W1    = (const float*)d_in[2];
    const float* b1    = (const float*)d_in[3];
    const float* W2    = (const float*)d_in[4];
    const float* b2    = (const float*)d_in[5];
    const float* gamma = (const float*)d_in[6];
    const float* beta  = (const float*)d_in[7];
    const float* W1f   = (const float*)d_in[8];
    const float* b1f   = (const float*)d_in[9];
    const float* W2f   = (const float*)d_in[10];
    const float* b2f   = (const float*)d_in[11];
    const int*   row   = (const int*)d_in[12];
    const int*   col   = (const int*)d_in[13];
    float* out = (float*)d_out;

    char* ws = (char*)d_ws;
    size_t off = 0;
    auto alloc = [&](size_t bytes) -> char* {
        char* p = ws + off;
        off += (bytes + 255) / 256 * 256;
        return p;
    };
    int*   rp    = (int*)  alloc((NN + 1) * sizeof(int));
    float* sums  = (float*)alloc(256 * sizeof(float));
    float* bufD1 = (float*)alloc((size_t)NN * DD * sizeof(float));
    float* bufD2 = (float*)alloc((size_t)NN * DD * sizeof(float));
    float* bufH1 = (float*)alloc((size_t)NN * HH * sizeof(float));
    float* bufH2 = (float*)alloc((size_t)NN * HH * sizeof(float));

    build_rowptr<<<(NN + 256) / 256, 256, 0, stream>>>(row, rp);

    const float* X = x;
    for (int l = 0; l < LL; l++) {
        gemm_dh<<<(NN + 15) / 16, 256, 0, stream>>>(X, W1 + l * DD * HH, bufH1);
        spmm<HH, 16, true><<<(NN + 15) / 16, 256, 0, stream>>>(rp, col, vals, bufH1, b1 + l * HH, bufH2);
        gemm_hd<<<2048, 256, 0, stream>>>(bufH2, W2 + l * HH * DD, bufD1);
        spmm<DD, 128, false><<<(NN + 1) / 2, 256, 0, stream>>>(rp, col, vals, bufD1, b2 + l * DD, bufD2);
        zero_sums<<<1, 256, 0, stream>>>(sums);
        bn_reduce<<<256, 256, 0, stream>>>(bufD2, sums);
        bn_apply<<<2048, 256, 0, stream>>>(bufD2, sums, gamma + l * DD, beta + l * DD, bufD1);
        X = bufD1;
    }
    gemm_dh<<<(NN + 15) / 16, 256, 0, stream>>>(X, W1f, bufH1);
    spmm<HH, 16, true><<<(NN + 15) / 16, 256, 0, stream>>>(rp, col, vals, bufH1, b1f, bufH2);
    gemm_hc<<<2048, 256, 0, stream>>>(bufH2, W2f, bufD1);
    spmm<CC, 64, false><<<(NN + 3) / 4, 256, 0, stream>>>(rp, col, vals, bufD1, b2f, out);
}

// Round 2
// 633.627 us; speedup vs baseline: 2.7893x; 2.7893x over previous
//
#include <hip/hip_runtime.h>

#define NN 100000
#define NE 1600000
#define DD 128
#define HH 16
#define CC 40
#define LL 3

__global__ void build_rowptr(const int* __restrict__ row, int* __restrict__ rp) {
    int i = blockIdx.x * blockDim.x + threadIdx.x;
    if (i > NN) return;
    int lo = 0, hi = NE;
    while (lo < hi) { int m = (lo + hi) >> 1; if (row[m] < i) lo = m + 1; else hi = m; }
    rp[i] = lo;
}

__global__ void zero_buf(float* __restrict__ s, int n) {
    int i = blockIdx.x * 256 + threadIdx.x;
    if (i < n) s[i] = 0.f;
}

// Y = X @ W  (N x 128) @ (128 x 16).  If BN: X := relu(X*sc + sh) on load,
// with sc/sh derived from running sums (fused bn_apply of the previous layer).
template <bool BN>
__launch_bounds__(256)
__global__ void gemm_dh(const float* __restrict__ X, const float* __restrict__ W,
                        const float* __restrict__ sums, const float* __restrict__ gamma,
                        const float* __restrict__ beta, float* __restrict__ out) {
    __shared__ float Ws[DD * HH];
    __shared__ float Xs[16 * 132];   // row stride 132: float4-aligned, 2-way-max banks
    __shared__ float sc[DD], sh[DD];
    int t = threadIdx.x;
    for (int i = t; i < DD * HH; i += 256) Ws[i] = W[i];
    if (BN) {
        if (t < DD) {
            float mean = sums[t] * (1.f / NN);
            float var  = sums[DD + t] * (1.f / NN) - mean * mean;
            float inv  = rsqrtf(var + 1e-5f);
            float g = gamma[t] * inv;
            sc[t] = g;
            sh[t] = beta[t] - mean * g;
        }
        __syncthreads();
    }
    int base = blockIdx.x * 16;                  // NN == 16*6250 exactly
    const float4* X4 = (const float4*)X;
    for (int i = t; i < 16 * 32; i += 256) {
        int r = i >> 5, cq = i & 31;
        float4 v = X4[(size_t)(base + r) * 32 + cq];
        if (BN) {
            int c = cq * 4;
            v.x = fmaxf(fmaf(v.x, sc[c + 0], sh[c + 0]), 0.f);
            v.y = fmaxf(fmaf(v.y, sc[c + 1], sh[c + 1]), 0.f);
            v.z = fmaxf(fmaf(v.z, sc[c + 2], sh[c + 2]), 0.f);
            v.w = fmaxf(fmaf(v.w, sc[c + 3], sh[c + 3]), 0.f);
        }
        *(float4*)(&Xs[r * 132 + cq * 4]) = v;
    }
    __syncthreads();
    int r = t >> 4, h = t & 15;
    float acc = 0.f;
    #pragma unroll
    for (int k = 0; k < DD; k++) acc = fmaf(Xs[r * 132 + k], Ws[k * HH + h], acc);
    out[(base + r) * HH + h] = acc;
}

// out[n][0:16] = (bias) + sum_e vals[e]*hin[col[e]][0:16], optional relu.
// 4 lanes/node, float4 gathers, 4-edge unroll for MLP.
template <bool RELU, bool BIAS>
__launch_bounds__(256)
__global__ void spmm16(const int* __restrict__ rp, const int* __restrict__ col,
                       const float* __restrict__ vals, const float* __restrict__ hin,
                       const float* __restrict__ bias, float* __restrict__ out) {
    int node = blockIdx.x * 64 + (threadIdx.x >> 2);
    int f = threadIdx.x & 3;
    if (node >= NN) return;
    int s = rp[node], e = rp[node + 1];
    const float4* h4 = (const float4*)hin;
    float ax = 0.f, ay = 0.f, az = 0.f, aw = 0.f;
    int j = s;
    for (; j + 3 < e; j += 4) {
        int c0 = col[j], c1 = col[j + 1], c2 = col[j + 2], c3 = col[j + 3];
        float v0 = vals[j], v1 = vals[j + 1], v2 = vals[j + 2], v3 = vals[j + 3];
        float4 a0 = h4[c0 * 4 + f];
        float4 a1 = h4[c1 * 4 + f];
        float4 a2 = h4[c2 * 4 + f];
        float4 a3 = h4[c3 * 4 + f];
        ax = fmaf(v0, a0.x, ax); ay = fmaf(v0, a0.y, ay); az = fmaf(v0, a0.z, az); aw = fmaf(v0, a0.w, aw);
        ax = fmaf(v1, a1.x, ax); ay = fmaf(v1, a1.y, ay); az = fmaf(v1, a1.z, az); aw = fmaf(v1, a1.w, aw);
        ax = fmaf(v2, a2.x, ax); ay = fmaf(v2, a2.y, ay); az = fmaf(v2, a2.z, az); aw = fmaf(v2, a2.w, aw);
        ax = fmaf(v3, a3.x, ax); ay = fmaf(v3, a3.y, ay); az = fmaf(v3, a3.z, az); aw = fmaf(v3, a3.w, aw);
    }
    for (; j < e; j++) {
        int c = col[j]; float v = vals[j];
        float4 a = h4[c * 4 + f];
        ax = fmaf(v, a.x, ax); ay = fmaf(v, a.y, ay); az = fmaf(v, a.z, az); aw = fmaf(v, a.w, aw);
    }
    if (BIAS) {
        float4 b = ((const float4*)bias)[f];
        ax += b.x; ay += b.y; az += b.z; aw += b.w;
    }
    if (RELU) {
        ax = fmaxf(ax, 0.f); ay = fmaxf(ay, 0.f); az = fmaxf(az, 0.f); aw = fmaxf(aw, 0.f);
    }
    float4 o = {ax, ay, az, aw};
    ((float4*)out)[node * 4 + f] = o;
}

// H = T @ W + bias  (N x 16) @ (16 x 128); fused BN-stat reduction into sums.
__launch_bounds__(256)
__global__ void gemm_hd_red(const float* __restrict__ T, const float* __restrict__ W,
                            const float* __restrict__ bias, float* __restrict__ out,
                            float* __restrict__ sums) {
    __shared__ float4 Ws4[HH * 32];
    __shared__ float4 Bs4[32];
    __shared__ float4 r1[256], r2[256];
    int t = threadIdx.x;
    for (int i = t; i < HH * 32; i += 256) Ws4[i] = ((const float4*)W)[i];
    if (t < 32) Bs4[t] = ((const float4*)bias)[t];
    __syncthreads();
    float4 s = {0, 0, 0, 0}, q = {0, 0, 0, 0};
    const int total = NN * 32;
    for (int id = blockIdx.x * 256 + t; id < total; id += gridDim.x * 256) {
        int n = id >> 5, dq = id & 31;       // stride is multiple of 32 -> dq fixed per thread
        const float* tr = T + n * HH;
        float4 acc = Bs4[dq];
        #pragma unroll
        for (int k = 0; k < HH; k++) {
            float tv = tr[k];
            float4 w = Ws4[k * 32 + dq];
            acc.x = fmaf(tv, w.x, acc.x);
            acc.y = fmaf(tv, w.y, acc.y);
            acc.z = fmaf(tv, w.z, acc.z);
            acc.w = fmaf(tv, w.w, acc.w);
        }
        ((float4*)out)[id] = acc;
        s.x += acc.x; s.y += acc.y; s.z += acc.z; s.w += acc.w;
        q.x += acc.x * acc.x; q.y += acc.y * acc.y; q.z += acc.z * acc.z; q.w += acc.w * acc.w;
    }
    r1[t] = s; r2[t] = q;
    __syncthreads();
    for (int st = 128; st >= 32; st >>= 1) {
        if (t < st) {
            float4 a = r1[t], b = r1[t + st];
            a.x += b.x; a.y += b.y; a.z += b.z; a.w += b.w; r1[t] = a;
            float4 c = r2[t], d = r2[t + st];
            c.x += d.x; c.y += d.y; c.z += d.z; c.w += d.w; r2[t] = c;
        }
        __syncthreads();
    }
    if (t < 32) {
        float4 a = r1[t], b = r2[t];
        atomicAdd(&sums[t * 4 + 0], a.x); atomicAdd(&sums[t * 4 + 1], a.y);
        atomicAdd(&sums[t * 4 + 2], a.z); atomicAdd(&sums[t * 4 + 3], a.w);
        atomicAdd(&sums[DD + t * 4 + 0], b.x); atomicAdd(&sums[DD + t * 4 + 1], b.y);
        atomicAdd(&sums[DD + t * 4 + 2], b.z); atomicAdd(&sums[DD + t * 4 + 3], b.w);
    }
}

// out = T @ W + bias  (N x 16) @ (16 x 40)
__launch_bounds__(256)
__global__ void gemm_hc(const float* __restrict__ T, const float* __restrict__ W,
                        const float* __restrict__ bias, float* __restrict__ out) {
    __shared__ float Ws[HH * CC];
    __shared__ float Bs[CC];
    for (int i = threadIdx.x; i < HH * CC; i += 256) Ws[i] = W[i];
    if (threadIdx.x < CC) Bs[threadIdx.x] = bias[threadIdx.x];
    __syncthreads();
    const int total = NN * CC;
    for (int id = blockIdx.x * 256 + threadIdx.x; id < total; id += gridDim.x * 256) {
        int n = id / CC, c = id - n * CC;
        const float* tr = T + n * HH;
        float acc = Bs[c];
        #pragma unroll
        for (int k = 0; k < HH; k++) acc = fmaf(tr[k], Ws[k * CC + c], acc);
        out[id] = acc;
    }
}

extern "C" void kernel_launch(void* const* d_in, const int* in_sizes, int n_in,
                              void* d_out, int out_size, void* d_ws, size_t ws_size,
                              hipStream_t stream) {
    const float* x     = (const float*)d_in[0];
    const float* vals  = (const float*)d_in[1];
    const float* W1    = (const float*)d_in[2];
    const float* b1    = (const float*)d_in[3];
    const float* W2    = (const float*)d_in[4];
    const float* b2    = (const float*)d_in[5];
    const float* gamma = (const float*)d_in[6];
    const float* beta  = (const float*)d_in[7];
    const float* W1f   = (const float*)d_in[8];
    const float* b1f   = (const float*)d_in[9];
    const float* W2f   = (const float*)d_in[10];
    const float* b2f   = (const float*)d_in[11];
    const int*   row   = (const int*)d_in[12];
    const int*   col   = (const int*)d_in[13];
    float* out = (float*)d_out;

    char* ws = (char*)d_ws;
    size_t off = 0;
    auto alloc = [&](size_t bytes) -> char* {
        char* p = ws + off;
        off += (bytes + 255) / 256 * 256;
        return p;
    };
    int*   rp   = (int*)  alloc((NN + 1) * sizeof(int));
    float* sums = (float*)alloc(LL * 256 * sizeof(float));
    float* H    = (float*)alloc((size_t)NN * DD * sizeof(float));
    float* Y    = (float*)alloc((size_t)NN * HH * sizeof(float));
    float* T    = (float*)alloc((size_t)NN * HH * sizeof(float));
    float* U    = (float*)alloc((size_t)NN * HH * sizeof(float));

    build_rowptr<<<(NN + 256) / 256, 256, 0, stream>>>(row, rp);
    zero_buf<<<3, 256, 0, stream>>>(sums, LL * 256);

    for (int l = 0; l < LL; l++) {
        if (l == 0)
            gemm_dh<false><<<NN / 16, 256, 0, stream>>>(x, W1, nullptr, nullptr, nullptr, Y);
        else
            gemm_dh<true><<<NN / 16, 256, 0, stream>>>(H, W1 + l * DD * HH,
                sums + (l - 1) * 256, gamma + (l - 1) * DD, beta + (l - 1) * DD, Y);
        spmm16<true, true><<<(NN + 63) / 64, 256, 0, stream>>>(rp, col, vals, Y, b1 + l * HH, T);
        spmm16<false, false><<<(NN + 63) / 64, 256, 0, stream>>>(rp, col, vals, T, nullptr, U);
        gemm_hd_red<<<512, 256, 0, stream>>>(U, W2 + l * HH * DD, b2 + l * DD, H, sums + l * 256);
    }
    // head: logits = spmm16(relu(spmm16(X@W1f)+b1f)) @ W2f + b2f
    gemm_dh<true><<<NN / 16, 256, 0, stream>>>(H, W1f,
        sums + (LL - 1) * 256, gamma + (LL - 1) * DD, beta + (LL - 1) * DD, Y);
    spmm16<true, true><<<(NN + 63) / 64, 256, 0, stream>>>(rp, col, vals, Y, b1f, T);
    spmm16<false, false><<<(NN + 63) / 64, 256, 0, stream>>>(rp, col, vals, T, nullptr, U);
    gemm_hc<<<2048, 256, 0, stream>>>(U, W2f, b2f, out);
}

// Round 3
// 523.725 us; speedup vs baseline: 3.3746x; 1.2098x over previous
//
#include <hip/hip_runtime.h>

#define NN 100000
#define NE 1600000
#define DD 128
#define HH 16
#define CC 40
#define LL 3

__device__ __forceinline__ float4 f4fma(float s, float4 w, float4 a) {
    a.x = fmaf(s, w.x, a.x); a.y = fmaf(s, w.y, a.y);
    a.z = fmaf(s, w.z, a.z); a.w = fmaf(s, w.w, a.w);
    return a;
}

__global__ void build_rowptr(const int* __restrict__ row, int* __restrict__ rp) {
    int i = blockIdx.x * blockDim.x + threadIdx.x;
    if (i > NN) return;
    int lo = 0, hi = NE;
    while (lo < hi) { int m = (lo + hi) >> 1; if (row[m] < i) lo = m + 1; else hi = m; }
    rp[i] = lo;
}

__global__ void zero_buf(float* __restrict__ s, int n) {
    int i = blockIdx.x * 256 + threadIdx.x;
    if (i < n) s[i] = 0.f;
}

// Y = X @ W  (N x 128)@(128 x 16), thread-per-node, W in LDS (broadcast reads)
__launch_bounds__(256)
__global__ void gemm_dh_reg(const float* __restrict__ X, const float* __restrict__ W,
                            float* __restrict__ Y) {
    __shared__ float4 Ws[DD * 4];   // W[d][h] as float4 over h
    int t = threadIdx.x;
    for (int i = t; i < DD * 4; i += 256) Ws[i] = ((const float4*)W)[i];
    __syncthreads();
    int n = blockIdx.x * 256 + t;
    if (n >= NN) return;
    const float4* X4 = (const float4*)(X + (size_t)n * DD);
    float4 y0 = {0,0,0,0}, y1 = {0,0,0,0}, y2 = {0,0,0,0}, y3 = {0,0,0,0};
    #pragma unroll 8
    for (int dc = 0; dc < 32; dc++) {
        float4 xv = X4[dc];
        float xs[4] = {xv.x, xv.y, xv.z, xv.w};
        #pragma unroll
        for (int j = 0; j < 4; j++) {
            int d = dc * 4 + j;
            float xj = xs[j];
            y0 = f4fma(xj, Ws[d * 4 + 0], y0);
            y1 = f4fma(xj, Ws[d * 4 + 1], y1);
            y2 = f4fma(xj, Ws[d * 4 + 2], y2);
            y3 = f4fma(xj, Ws[d * 4 + 3], y3);
        }
    }
    float4* Yp = (float4*)(Y + (size_t)n * HH);
    Yp[0] = y0; Yp[1] = y1; Yp[2] = y2; Yp[3] = y3;
}

// out[n][0:16] = (bias) + sum_e vals[e]*hin[col[e]][0:16], optional relu.
template <bool RELU, bool BIAS>
__launch_bounds__(256)
__global__ void spmm16(const int* __restrict__ rp, const int* __restrict__ col,
                       const float* __restrict__ vals, const float* __restrict__ hin,
                       const float* __restrict__ bias, float* __restrict__ out) {
    int node = blockIdx.x * 64 + (threadIdx.x >> 2);
    int f = threadIdx.x & 3;
    if (node >= NN) return;
    int s = rp[node], e = rp[node + 1];
    const float4* h4 = (const float4*)hin;
    float ax = 0.f, ay = 0.f, az = 0.f, aw = 0.f;
    int j = s;
    for (; j + 3 < e; j += 4) {
        int c0 = col[j], c1 = col[j + 1], c2 = col[j + 2], c3 = col[j + 3];
        float v0 = vals[j], v1 = vals[j + 1], v2 = vals[j + 2], v3 = vals[j + 3];
        float4 a0 = h4[c0 * 4 + f];
        float4 a1 = h4[c1 * 4 + f];
        float4 a2 = h4[c2 * 4 + f];
        float4 a3 = h4[c3 * 4 + f];
        ax = fmaf(v0, a0.x, ax); ay = fmaf(v0, a0.y, ay); az = fmaf(v0, a0.z, az); aw = fmaf(v0, a0.w, aw);
        ax = fmaf(v1, a1.x, ax); ay = fmaf(v1, a1.y, ay); az = fmaf(v1, a1.z, az); aw = fmaf(v1, a1.w, aw);
        ax = fmaf(v2, a2.x, ax); ay = fmaf(v2, a2.y, ay); az = fmaf(v2, a2.z, az); aw = fmaf(v2, a2.w, aw);
        ax = fmaf(v3, a3.x, ax); ay = fmaf(v3, a3.y, ay); az = fmaf(v3, a3.z, az); aw = fmaf(v3, a3.w, aw);
    }
    for (; j < e; j++) {
        int c = col[j]; float v = vals[j];
        float4 a = h4[c * 4 + f];
        ax = fmaf(v, a.x, ax); ay = fmaf(v, a.y, ay); az = fmaf(v, a.z, az); aw = fmaf(v, a.w, aw);
    }
    if (BIAS) {
        float4 b = ((const float4*)bias)[f];
        ax += b.x; ay += b.y; az += b.z; aw += b.w;
    }
    if (RELU) {
        ax = fmaxf(ax, 0.f); ay = fmaxf(ay, 0.f); az = fmaxf(az, 0.f); aw = fmaxf(aw, 0.f);
    }
    float4 o = {ax, ay, az, aw};
    ((float4*)out)[node * 4 + f] = o;
}

// GS[0..255] = G = U^T U (k'*16+k), GS[256..271] = s = colsum(U)
__launch_bounds__(256)
__global__ void stats_gram(const float* __restrict__ U, float* __restrict__ GS) {
    __shared__ float Us[64 * 20];   // row stride 20 floats (80B: float4-aligned, bank-spread)
    int t = threadIdx.x;
    int k = t & 15, kp = t >> 4;
    float g = 0.f, s = 0.f;
    const int npb = (NN + gridDim.x - 1) / gridDim.x;
    int n0 = blockIdx.x * npb;
    int n1 = min(n0 + npb, NN);
    for (int nb = n0; nb < n1; nb += 64) {
        int cnt = min(64, n1 - nb);
        __syncthreads();
        for (int i = t; i < cnt * 4; i += 256) {
            int r = i >> 2, q = i & 3;
            ((float4*)&Us[r * 20])[q] = ((const float4*)(U + (size_t)(nb + r) * HH))[q];
        }
        __syncthreads();
        for (int n = 0; n < cnt; n++) {
            float a = Us[n * 20 + k];
            float b = Us[n * 20 + kp];
            g = fmaf(a, b, g);
            s += a;
        }
    }
    atomicAdd(&GS[kp * 16 + k], g);
    if (kp == 0) atomicAdd(&GS[256 + k], s);
}

// Y = relu(BN(U @ W2 + b2)) @ W1n ; BN stats reconstructed from G,s (no H in memory)
__launch_bounds__(256)
__global__ void fused_mid(const float* __restrict__ U, const float* __restrict__ GS,
                          const float* __restrict__ W2, const float* __restrict__ b2,
                          const float* __restrict__ gamma, const float* __restrict__ beta,
                          const float* __restrict__ W1n, float* __restrict__ Y) {
    __shared__ float4 W2s[HH * 32];   // W2[k][d] as float4 over d
    __shared__ float4 W1s[DD * 4];    // W1n[d][h] as float4 over h
    __shared__ float4 b2s[32];
    __shared__ float  Gs[272];
    __shared__ float  sc[DD], sh[DD];
    int t = threadIdx.x;
    for (int i = t; i < HH * 32; i += 256) W2s[i] = ((const float4*)W2)[i];
    for (int i = t; i < DD * 4; i += 256) W1s[i] = ((const float4*)W1n)[i];
    if (t < 32) b2s[t] = ((const float4*)b2)[t];
    for (int i = t; i < 272; i += 256) Gs[i] = GS[i];
    __syncthreads();
    if (t < DD) {
        int d = t;
        const float* W2f = (const float*)W2s;
        float w[16];
        #pragma unroll
        for (int k = 0; k < 16; k++) w[k] = W2f[k * DD + d];
        float sdot = 0.f, quad = 0.f;
        #pragma unroll
        for (int k = 0; k < 16; k++) {
            sdot = fmaf(Gs[256 + k], w[k], sdot);
            float vk = 0.f;
            #pragma unroll
            for (int kp = 0; kp < 16; kp++) vk = fmaf(Gs[k * 16 + kp], w[kp], vk);
            quad = fmaf(w[k], vk, quad);
        }
        float b = ((const float*)b2s)[d];
        float sumH  = sdot + (float)NN * b;
        float sumsq = quad + 2.f * b * sdot + (float)NN * b * b;
        float mean = sumH * (1.f / NN);
        float var  = sumsq * (1.f / NN) - mean * mean;
        float inv  = rsqrtf(var + 1e-5f);
        float gmm  = gamma[d] * inv;
        sc[d] = gmm;
        sh[d] = beta[d] - mean * gmm;
    }
    __syncthreads();
    int n0 = blockIdx.x * 512 + t;
    int n1 = n0 + 256;
    bool v0 = n0 < NN, v1 = n1 < NN;
    float ua[16], ub[16];
    #pragma unroll
    for (int k = 0; k < 16; k++) { ua[k] = 0.f; ub[k] = 0.f; }
    if (v0) {
        const float4* p = (const float4*)(U + (size_t)n0 * HH);
        float4 a = p[0], b = p[1], c = p[2], d = p[3];
        ua[0]=a.x; ua[1]=a.y; ua[2]=a.z; ua[3]=a.w; ua[4]=b.x; ua[5]=b.y; ua[6]=b.z; ua[7]=b.w;
        ua[8]=c.x; ua[9]=c.y; ua[10]=c.z; ua[11]=c.w; ua[12]=d.x; ua[13]=d.y; ua[14]=d.z; ua[15]=d.w;
    }
    if (v1) {
        const float4* p = (const float4*)(U + (size_t)n1 * HH);
        float4 a = p[0], b = p[1], c = p[2], d = p[3];
        ub[0]=a.x; ub[1]=a.y; ub[2]=a.z; ub[3]=a.w; ub[4]=b.x; ub[5]=b.y; ub[6]=b.z; ub[7]=b.w;
        ub[8]=c.x; ub[9]=c.y; ub[10]=c.z; ub[11]=c.w; ub[12]=d.x; ub[13]=d.y; ub[14]=d.z; ub[15]=d.w;
    }
    float4 ya[4], yb[4];
    #pragma unroll
    for (int q = 0; q < 4; q++) { ya[q] = {0,0,0,0}; yb[q] = {0,0,0,0}; }
    #pragma unroll 4
    for (int dq = 0; dq < 32; dq++) {
        float4 h0 = b2s[dq], h1 = h0;
        #pragma unroll
        for (int k = 0; k < 16; k++) {
            float4 w = W2s[k * 32 + dq];
            h0 = f4fma(ua[k], w, h0);
            h1 = f4fma(ub[k], w, h1);
        }
        float4 s4 = *(const float4*)&sc[dq * 4];
        float4 t4 = *(const float4*)&sh[dq * 4];
        h0.x = fmaxf(fmaf(h0.x, s4.x, t4.x), 0.f); h0.y = fmaxf(fmaf(h0.y, s4.y, t4.y), 0.f);
        h0.z = fmaxf(fmaf(h0.z, s4.z, t4.z), 0.f); h0.w = fmaxf(fmaf(h0.w, s4.w, t4.w), 0.f);
        h1.x = fmaxf(fmaf(h1.x, s4.x, t4.x), 0.f); h1.y = fmaxf(fmaf(h1.y, s4.y, t4.y), 0.f);
        h1.z = fmaxf(fmaf(h1.z, s4.z, t4.z), 0.f); h1.w = fmaxf(fmaf(h1.w, s4.w, t4.w), 0.f);
        float ha[4] = {h0.x, h0.y, h0.z, h0.w};
        float hb[4] = {h1.x, h1.y, h1.z, h1.w};
        #pragma unroll
        for (int j = 0; j < 4; j++) {
            int d = dq * 4 + j;
            float4 w0 = W1s[d * 4 + 0], w1 = W1s[d * 4 + 1], w2 = W1s[d * 4 + 2], w3 = W1s[d * 4 + 3];
            ya[0] = f4fma(ha[j], w0, ya[0]); ya[1] = f4fma(ha[j], w1, ya[1]);
            ya[2] = f4fma(ha[j], w2, ya[2]); ya[3] = f4fma(ha[j], w3, ya[3]);
            yb[0] = f4fma(hb[j], w0, yb[0]); yb[1] = f4fma(hb[j], w1, yb[1]);
            yb[2] = f4fma(hb[j], w2, yb[2]); yb[3] = f4fma(hb[j], w3, yb[3]);
        }
    }
    if (v0) {
        float4* Yp = (float4*)(Y + (size_t)n0 * HH);
        Yp[0] = ya[0]; Yp[1] = ya[1]; Yp[2] = ya[2]; Yp[3] = ya[3];
    }
    if (v1) {
        float4* Yp = (float4*)(Y + (size_t)n1 * HH);
        Yp[0] = yb[0]; Yp[1] = yb[1]; Yp[2] = yb[2]; Yp[3] = yb[3];
    }
}

// out = U @ W + bias  (N x 16)@(16 x 40), thread-per-node
__launch_bounds__(256)
__global__ void gemm_hc_reg(const float* __restrict__ U, const float* __restrict__ W,
                            const float* __restrict__ bias, float* __restrict__ out) {
    __shared__ float4 Ws[HH * 10];   // W[k][c] as float4 over c
    __shared__ float4 Bs[10];
    int t = threadIdx.x;
    for (int i = t; i < HH * 10; i += 256) Ws[i] = ((const float4*)W)[i];
    if (t < 10) Bs[t] = ((const float4*)bias)[t];
    __syncthreads();
    int n = blockIdx.x * 256 + t;
    if (n >= NN) return;
    float u[16];
    {
        const float4* p = (const float4*)(U + (size_t)n * HH);
        float4 a = p[0], b = p[1], c = p[2], d = p[3];
        u[0]=a.x; u[1]=a.y; u[2]=a.z; u[3]=a.w; u[4]=b.x; u[5]=b.y; u[6]=b.z; u[7]=b.w;
        u[8]=c.x; u[9]=c.y; u[10]=c.z; u[11]=c.w; u[12]=d.x; u[13]=d.y; u[14]=d.z; u[15]=d.w;
    }
    float4 acc[10];
    #pragma unroll
    for (int q = 0; q < 10; q++) acc[q] = Bs[q];
    #pragma unroll
    for (int k = 0; k < 16; k++) {
        float uk = u[k];
        #pragma unroll
        for (int q = 0; q < 10; q++) acc[q] = f4fma(uk, Ws[k * 10 + q], acc[q]);
    }
    float4* O = (float4*)(out + (size_t)n * CC);
    #pragma unroll
    for (int q = 0; q < 10; q++) O[q] = acc[q];
}

extern "C" void kernel_launch(void* const* d_in, const int* in_sizes, int n_in,
                              void* d_out, int out_size, void* d_ws, size_t ws_size,
                              hipStream_t stream) {
    const float* x     = (const float*)d_in[0];
    const float* vals  = (const float*)d_in[1];
    const float* W1    = (const float*)d_in[2];
    const float* b1    = (const float*)d_in[3];
    const float* W2    = (const float*)d_in[4];
    const float* b2    = (const float*)d_in[5];
    const float* gamma = (const float*)d_in[6];
    const float* beta  = (const float*)d_in[7];
    const float* W1f   = (const float*)d_in[8];
    const float* b1f   = (const float*)d_in[9];
    const float* W2f   = (const float*)d_in[10];
    const float* b2f   = (const float*)d_in[11];
    const int*   row   = (const int*)d_in[12];
    const int*   col   = (const int*)d_in[13];
    float* out = (float*)d_out;

    char* ws = (char*)d_ws;
    size_t off = 0;
    auto alloc = [&](size_t bytes) -> char* {
        char* p = ws + off;
        off += (bytes + 255) / 256 * 256;
        return p;
    };
    int*   rp = (int*)  alloc((NN + 1) * sizeof(int));
    float* GS = (float*)alloc(LL * 272 * sizeof(float));
    float* Y  = (float*)alloc((size_t)NN * HH * sizeof(float));
    float* T  = (float*)alloc((size_t)NN * HH * sizeof(float));
    float* U  = (float*)alloc((size_t)NN * HH * sizeof(float));

    build_rowptr<<<(NN + 256) / 256, 256, 0, stream>>>(row, rp);
    zero_buf<<<(LL * 272 + 255) / 256, 256, 0, stream>>>(GS, LL * 272);

    gemm_dh_reg<<<(NN + 255) / 256, 256, 0, stream>>>(x, W1, Y);
    for (int l = 0; l < LL; l++) {
        spmm16<true, true><<<(NN + 63) / 64, 256, 0, stream>>>(rp, col, vals, Y, b1 + l * HH, T);
        spmm16<false, false><<<(NN + 63) / 64, 256, 0, stream>>>(rp, col, vals, T, nullptr, U);
        stats_gram<<<256, 256, 0, stream>>>(U, GS + l * 272);
        const float* W1next = (l < LL - 1) ? (W1 + (l + 1) * DD * HH) : W1f;
        fused_mid<<<(NN + 511) / 512, 256, 0, stream>>>(U, GS + l * 272,
            W2 + l * HH * DD, b2 + l * DD, gamma + l * DD, beta + l * DD, W1next, Y);
    }
    spmm16<true, true><<<(NN + 63) / 64, 256, 0, stream>>>(rp, col, vals, Y, b1f, T);
    spmm16<false, false><<<(NN + 63) / 64, 256, 0, stream>>>(rp, col, vals, T, nullptr, U);
    gemm_hc_reg<<<(NN + 255) / 256, 256, 0, stream>>>(U, W2f, b2f, out);
}